// Round 3
// baseline (804.346 us; speedup 1.0000x reference)
//
#include <hip/hip_runtime.h>
#include <stdint.h>

// MultiheadCorrelation: T=8192, B=4, D=1024, H=16, hd=64. fp32 I/O, bf16 MFMA inside.
// cvt -> GEMM1 (qkv; q,k transposed [bh][d][t], v [t*4+b][1024]) -> stats (MFMA, partials)
// -> finalize (corr softmax -> corrT bf16) -> attn (v@corr MFMA) -> GEMM2 (fp32 out).

typedef unsigned short u16;
typedef __attribute__((ext_vector_type(8))) short bf16x8;
typedef __attribute__((ext_vector_type(8))) u16  u16x8;
typedef __attribute__((ext_vector_type(4))) float f32x4;

#define AS1 __attribute__((address_space(1)))
#define AS3 __attribute__((address_space(3)))

__device__ __forceinline__ u16 f2b(float f) {
  union { float f; uint32_t u; } x; x.f = f;
  const uint32_t u = x.u;
  return (u16)((u + 0x7FFFu + ((u >> 16) & 1u)) >> 16);  // RNE
}
__device__ __forceinline__ void g2l16(const void* g, void* l) {
  __builtin_amdgcn_global_load_lds((const AS1 uint32_t*)g, (AS3 uint32_t*)l, 16, 0, 0);
}

// ---------------------------------------------------------------------------
// fused fp32->bf16 convert for query / Wqkv / Wout (one launch)
// groups of 8 elems: query 4194304, Wqkv 393216, Wout 131072  (total 4718592)
// ---------------------------------------------------------------------------
__global__ __launch_bounds__(256) void cvt_all(
    const float* __restrict__ q, const float* __restrict__ w1, const float* __restrict__ w2,
    u16* __restrict__ qb, u16* __restrict__ w1b, u16* __restrict__ w2b)
{
  int i = blockIdx.x * 256 + threadIdx.x;
  if (i >= 4718592) return;
  const float* s; u16* d; int ofs;
  if (i < 4194304)      { s = q;  d = qb;  ofs = i; }
  else if (i < 4587520) { s = w1; d = w1b; ofs = i - 4194304; }
  else                  { s = w2; d = w2b; ofs = i - 4587520; }
  const float4 a = *(const float4*)(s + (size_t)ofs * 8);
  const float4 b = *(const float4*)(s + (size_t)ofs * 8 + 4);
  u16x8 o;
  o[0] = f2b(a.x); o[1] = f2b(a.y); o[2] = f2b(a.z); o[3] = f2b(a.w);
  o[4] = f2b(b.x); o[5] = f2b(b.y); o[6] = f2b(b.z); o[7] = f2b(b.w);
  *(u16x8*)(d + (size_t)ofs * 8) = o;
}

// ---------------------------------------------------------------------------
// GEMM: C[m,n] = sum_k A[m,k]*Bw[n,k] + bias[n]. 128x128 tile, BK=64,
// 4 waves of 64x64, mfma 16x16x32 bf16. XOR swizzle on k-block vs row&7.
// MODE 1: seg=col>>10: q,k -> transposed [seg][bh][d][t] bf16; v -> [m][1024] bf16.
// MODE 2: fp32 [M,N].
// ---------------------------------------------------------------------------
template <int MODE>
__global__ __launch_bounds__(256) void gemm_bt(
    const u16* __restrict__ A, const u16* __restrict__ Bw,
    const float* __restrict__ bias, void* __restrict__ OutP,
    int M, int N, int K, int nTilesN)
{
  __shared__ __align__(16) u16 As[128 * 64];   // 16 KB
  __shared__ __align__(16) u16 Bs[128 * 64];
  const int tid = threadIdx.x;
  const int bn = blockIdx.x % nTilesN;
  const int bm = blockIdx.x / nTilesN;
  const int m0 = bm * 128, n0 = bn * 128;
  const int lane = tid & 63, wave = tid >> 6;
  const int wm = (wave >> 1) * 64, wn = (wave & 1) * 64;
  const int laneN = lane & 15, laneQ = lane >> 4;

  // staging: 4 issues/matrix; chunk c = tid + i*256: row=c>>3, slot=c&7,
  // logical kb = slot ^ (row&7). issue delta: +32 rows (row&7 unchanged).
  const int srow = tid >> 3;
  const int skb  = (tid & 7) ^ (srow & 7);
  const u16* gA = A  + (size_t)(m0 + srow) * K + skb * 8;
  const u16* gB = Bw + (size_t)(n0 + srow) * K + skb * 8;
  u16* lA = &As[tid * 8];
  u16* lB = &Bs[tid * 8];

  f32x4 acc[4][4] = {};

  for (int kt = 0; kt < K; kt += 64) {
    __syncthreads();
#pragma unroll
    for (int i = 0; i < 4; ++i) {
      g2l16(gA + kt + (size_t)(i * 32) * K, lA + i * 2048);
      g2l16(gB + kt + (size_t)(i * 32) * K, lB + i * 2048);
    }
    __syncthreads();
#pragma unroll
    for (int ks2 = 0; ks2 < 2; ++ks2) {
      bf16x8 af[4], bf[4];
#pragma unroll
      for (int i = 0; i < 4; ++i) {
        const int row = wm + i * 16 + laneN;
        const int kq  = (ks2 * 4 + laneQ) ^ (row & 7);
        af[i] = *(const bf16x8*)&As[row * 64 + kq * 8];
      }
#pragma unroll
      for (int j = 0; j < 4; ++j) {
        const int row = wn + j * 16 + laneN;
        const int kq  = (ks2 * 4 + laneQ) ^ (row & 7);
        bf[j] = *(const bf16x8*)&Bs[row * 64 + kq * 8];
      }
#pragma unroll
      for (int i = 0; i < 4; ++i)
#pragma unroll
        for (int j = 0; j < 4; ++j)
          acc[i][j] = __builtin_amdgcn_mfma_f32_16x16x32_bf16(af[i], bf[j], acc[i][j], 0, 0, 0);
    }
  }

#pragma unroll
  for (int i = 0; i < 4; ++i) {
#pragma unroll
    for (int j = 0; j < 4; ++j) {
      const int col = n0 + wn + j * 16 + laneN;
      const float bv = bias[col];
#pragma unroll
      for (int r = 0; r < 4; ++r) {
        const int row = m0 + wm + i * 16 + laneQ * 4 + r;  // C/D: col=lane&15, row=quad*4+r
        const float v = acc[i][j][r] + bv;
        if (MODE == 1) {
          const int seg = col >> 10, cc = col & 1023;
          if (seg == 2) {               // v: [m][1024]
            ((u16*)OutP)[(size_t)67108864 + (size_t)row * 1024 + cc] = f2b(v);
          } else {                      // q,k: [seg][b*16+h][d][t]
            const int b = row & 3, t = row >> 2;
            const int h = cc >> 6, d = cc & 63;
            ((u16*)OutP)[(size_t)seg * 33554432 +
                         ((size_t)((b * 16 + h) * 64 + d)) * 8192 + t] = f2b(v);
          }
        } else {
          ((float*)OutP)[(size_t)row * N + col] = v;
        }
      }
    }
  }
}

// ---------------------------------------------------------------------------
// Stats (MFMA): per (b,h) S[d][e]=sum_t q_d k_e, Sq, Sqq, Sk, Skk.
// qT,kT are [bh][64 d][8192 t] bf16. grid = 64 bh * 8 chunks (1024 t), block 256.
// Each wave owns one 64t tile per round (4 rounds). Writes per-chunk partials.
// ---------------------------------------------------------------------------
__global__ __launch_bounds__(256) void stats_k(
    const u16* __restrict__ qT, const u16* __restrict__ kT,
    float* __restrict__ Spart, float* __restrict__ Mpart)
{
  __shared__ __align__(16) u16 smem[2 * 4 * 64 * 64];  // Qs | Ks, 64 KB
  __shared__ float margLDS[4 * 256];
  u16* Qs = smem;
  u16* Ks = smem + 16384;
  const int tid = threadIdx.x;
  const int bh = blockIdx.x & 63;
  const int chunk = blockIdx.x >> 6;
  const int t0 = chunk * 1024;
  const int lane = tid & 63, wave = tid >> 6;
  const int laneN = lane & 15, laneQ = lane >> 4;

  const u16* qp = qT + (size_t)bh * 524288;
  const u16* kp = kT + (size_t)bh * 524288;

  f32x4 accS[4][4] = {};
  f32x4 accQQ[4] = {}, accKK[4] = {}, accQ1[4] = {}, accK1[4] = {};
  bf16x8 ones;
#pragma unroll
  for (int j = 0; j < 8; ++j) ones[j] = (short)0x3F80;   // bf16 1.0

  for (int rd = 0; rd < 4; ++rd) {
    __syncthreads();
#pragma unroll
    for (int i = 0; i < 8; ++i) {
      const int c = tid + i * 256;               // [tile(4)][d(64)][slot(8)]
      const int tile = c >> 9, cw = c & 511;
      const int d = cw >> 3, slot = cw & 7;
      const int kb = slot ^ (d & 7);
      const size_t gofs = (size_t)d * 8192 + (t0 + rd * 256 + tile * 64 + kb * 8);
      g2l16(qp + gofs, &Qs[c * 8]);
      g2l16(kp + gofs, &Ks[c * 8]);
    }
    __syncthreads();
    const u16* qt = &Qs[wave * 4096];
    const u16* kt2 = &Ks[wave * 4096];
#pragma unroll
    for (int ks2 = 0; ks2 < 2; ++ks2) {
      bf16x8 qf[4], kf[4];
#pragma unroll
      for (int i = 0; i < 4; ++i) {
        const int d = i * 16 + laneN;
        const int kq = (ks2 * 4 + laneQ) ^ (d & 7);
        qf[i] = *(const bf16x8*)&qt[d * 64 + kq * 8];
        kf[i] = *(const bf16x8*)&kt2[d * 64 + kq * 8];
      }
#pragma unroll
      for (int i = 0; i < 4; ++i) {
#pragma unroll
        for (int j = 0; j < 4; ++j)
          accS[i][j] = __builtin_amdgcn_mfma_f32_16x16x32_bf16(qf[i], kf[j], accS[i][j], 0, 0, 0);
        accQQ[i] = __builtin_amdgcn_mfma_f32_16x16x32_bf16(qf[i], qf[i], accQQ[i], 0, 0, 0);
        accKK[i] = __builtin_amdgcn_mfma_f32_16x16x32_bf16(kf[i], kf[i], accKK[i], 0, 0, 0);
        accQ1[i] = __builtin_amdgcn_mfma_f32_16x16x32_bf16(qf[i], ones, accQ1[i], 0, 0, 0);
        accK1[i] = __builtin_amdgcn_mfma_f32_16x16x32_bf16(kf[i], ones, accK1[i], 0, 0, 0);
      }
    }
  }

  // cross-wave reduction via LDS (reuse smem as 4*4096 floats)
  __syncthreads();
  float* red = (float*)smem;
#pragma unroll
  for (int i = 0; i < 4; ++i)
#pragma unroll
    for (int j = 0; j < 4; ++j)
#pragma unroll
      for (int r = 0; r < 4; ++r) {
        const int d = i * 16 + laneQ * 4 + r, e = j * 16 + laneN;
        red[wave * 4096 + d * 64 + e] = accS[i][j][r];
      }
#pragma unroll
  for (int i = 0; i < 4; ++i) {
    if (laneN == 0) {
#pragma unroll
      for (int r = 0; r < 4; ++r) {
        const int d = i * 16 + laneQ * 4 + r;    // Sq/Sk: any column of ones-MFMA
        margLDS[wave * 256 + 0 * 64 + d] = accQ1[i][r];
        margLDS[wave * 256 + 2 * 64 + d] = accK1[i][r];
      }
    }
    if ((laneN >> 2) == laneQ) {                 // diagonal of QQ^T / KK^T blocks
      const int r = laneN & 3;
      const int d = i * 16 + laneN;
      margLDS[wave * 256 + 1 * 64 + d] = accQQ[i][r];
      margLDS[wave * 256 + 3 * 64 + d] = accKK[i][r];
    }
  }
  __syncthreads();
  float* Sp = Spart + ((size_t)chunk * 64 + bh) * 4096;
  for (int c = tid; c < 4096; c += 256)
    Sp[c] = red[c] + red[4096 + c] + red[8192 + c] + red[12288 + c];
  float* Mp = Mpart + ((size_t)chunk * 64 + bh) * 256;
  Mp[tid] = margLDS[tid] + margLDS[256 + tid] + margLDS[512 + tid] + margLDS[768 + tid];
}

// ---------------------------------------------------------------------------
// Finalize: sum 8 partials; corr=clip(cov/sqrt(sx sy),0,1); softmax over d;
// store corrT[e][d] bf16. grid 64 (bh), block 64 (e).
// ---------------------------------------------------------------------------
__global__ __launch_bounds__(64) void finalize_k(
    const float* __restrict__ Spart, const float* __restrict__ Mpart,
    u16* __restrict__ corrT)
{
  __shared__ float Ss[4096];
  __shared__ float sqs[64], sxs[64];
  const int bh = blockIdx.x;
  const int e = threadIdx.x;
  for (int idx = e; idx < 4096; idx += 64) {
    float s = 0.f;
#pragma unroll
    for (int c = 0; c < 8; ++c) s += Spart[((size_t)c * 64 + bh) * 4096 + idx];
    Ss[idx] = s;
  }
  float m[4];
#pragma unroll
  for (int p = 0; p < 4; ++p) {
    float s = 0.f;
#pragma unroll
    for (int c = 0; c < 8; ++c) s += Mpart[((size_t)c * 64 + bh) * 256 + p * 64 + e];
    m[p] = s;
  }
  const float invT = 1.0f / 8192.0f;
  const float sy = m[3] - m[2] * m[2] * invT;
  const float ske = m[2];
  sqs[e] = m[0];
  sxs[e] = m[1] - m[0] * m[0] * invT;
  __syncthreads();
  float mx = 0.0f;
  for (int d = 0; d < 64; ++d) {
    const float c = Ss[d * 64 + e] - sqs[d] * ske * invT;
    float r = c / sqrtf(sxs[d] * sy);
    r = fminf(fmaxf(r, 0.0f), 1.0f);
    Ss[d * 64 + e] = r;
    mx = fmaxf(mx, r);
  }
  float sum = 0.f;
  for (int d = 0; d < 64; ++d) {
    const float ev = expf(Ss[d * 64 + e] - mx);
    Ss[d * 64 + e] = ev;
    sum += ev;
  }
  const float inv = 1.0f / sum;
  for (int d = 0; d < 64; ++d)
    corrT[(size_t)bh * 4096 + e * 64 + d] = f2b(Ss[d * 64 + e] * inv);
}

// ---------------------------------------------------------------------------
// Attn: attn[t,e] = sum_d v[t,d]*corr[d,e] per (b,h). A=v, B^T=corrT.
// grid = 64 bh * 32 t-tiles(256), block 256.
// ---------------------------------------------------------------------------
__global__ __launch_bounds__(256) void attn_k(
    const u16* __restrict__ vb, const u16* __restrict__ corrT,
    u16* __restrict__ attnb)
{
  __shared__ __align__(16) u16 Vs[256 * 64];   // 32 KB
  __shared__ __align__(16) u16 Cs[64 * 64];    // 8 KB
  const int tid = threadIdx.x;
  const int bh = blockIdx.x & 63;
  const int tt0 = (blockIdx.x >> 6) * 256;
  const int b = bh >> 4, h = bh & 15;
  const int lane = tid & 63, wave = tid >> 6;
  const int laneN = lane & 15, laneQ = lane >> 4;

  {
#pragma unroll
    for (int i = 0; i < 8; ++i) {
      const int c = tid + i * 256;              // [row(256)][slot(8)]
      const int row = c >> 3, slot = c & 7;
      const int kb = slot ^ (row & 7);
      const u16* g = vb + (size_t)((tt0 + row) * 4 + b) * 1024 + h * 64 + kb * 8;
      g2l16(g, &Vs[c * 8]);
    }
#pragma unroll
    for (int i = 0; i < 2; ++i) {
      const int c = tid + i * 256;              // [row(64)][slot(8)]
      const int row = c >> 3, slot = c & 7;
      const int kb = slot ^ (row & 7);
      g2l16(corrT + (size_t)bh * 4096 + row * 64 + kb * 8, &Cs[c * 8]);
    }
  }
  __syncthreads();

  const int wt = wave * 64;
  f32x4 acc[4][4] = {};
#pragma unroll
  for (int ks2 = 0; ks2 < 2; ++ks2) {
    bf16x8 af[4], bf[4];
#pragma unroll
    for (int i = 0; i < 4; ++i) {
      const int row = wt + i * 16 + laneN;
      const int kq = (ks2 * 4 + laneQ) ^ (row & 7);
      af[i] = *(const bf16x8*)&Vs[row * 64 + kq * 8];
    }
#pragma unroll
    for (int j = 0; j < 4; ++j) {
      const int row = j * 16 + laneN;
      const int kq = (ks2 * 4 + laneQ) ^ (row & 7);
      bf[j] = *(const bf16x8*)&Cs[row * 64 + kq * 8];
    }
#pragma unroll
    for (int i = 0; i < 4; ++i)
#pragma unroll
      for (int j = 0; j < 4; ++j)
        acc[i][j] = __builtin_amdgcn_mfma_f32_16x16x32_bf16(af[i], bf[j], acc[i][j], 0, 0, 0);
  }
#pragma unroll
  for (int i = 0; i < 4; ++i)
#pragma unroll
    for (int j = 0; j < 4; ++j)
#pragma unroll
      for (int r = 0; r < 4; ++r) {
        const int t = tt0 + wt + i * 16 + laneQ * 4 + r;
        const int e = j * 16 + laneN;
        attnb[(size_t)(t * 4 + b) * 1024 + h * 64 + e] = f2b(acc[i][j][r]);
      }
}

// ---------------------------------------------------------------------------
// ws layout (bytes):
//   0          qT   [64bh][64][8192] bf16 (64 MiB) -> reused as attn out [32768][1024]
//   67108864   kT   (64 MiB)
//   134217728  vb   [32768][1024] bf16 (64 MiB)
//   201326592  queryb (64 MiB)  -- aliased after GEMM1 by:
//     201326592  Spart 8*64*4096 f32 (8 MiB)
//     209715200  Mpart 8*64*256 f32 (512 KiB)
//     210239488  corrT 64*4096 bf16 (512 KiB)
//   268435456  Wqkvb (6 MiB)
//   274726912  Woutb (2 MiB)          total 276824064 B
// ---------------------------------------------------------------------------
extern "C" void kernel_launch(void* const* d_in, const int* in_sizes, int n_in,
                              void* d_out, int out_size, void* d_ws, size_t ws_size,
                              hipStream_t stream)
{
  const float* query = (const float*)d_in[0];
  const float* Wqkv  = (const float*)d_in[1];
  const float* bqkv  = (const float*)d_in[2];
  const float* Wout  = (const float*)d_in[3];
  const float* bout  = (const float*)d_in[4];
  char* ws = (char*)d_ws;

  u16*   qT     = (u16*)(ws);
  u16*   kT     = (u16*)(ws + 67108864);
  u16*   vb     = (u16*)(ws + 134217728);
  u16*   queryb = (u16*)(ws + 201326592);
  float* Spart  = (float*)(ws + 201326592);
  float* Mpart  = (float*)(ws + 209715200);
  u16*   corrT  = (u16*)(ws + 210239488);
  u16*   Wqkvb  = (u16*)(ws + 268435456);
  u16*   Woutb  = (u16*)(ws + 274726912);

  cvt_all<<<dim3(18432), dim3(256), 0, stream>>>(query, Wqkv, Wout, queryb, Wqkvb, Woutb);

  gemm_bt<1><<<dim3(6144), dim3(256), 0, stream>>>(queryb, Wqkvb, bqkv, qT,
                                                   32768, 3072, 1024, 24);
  stats_k<<<dim3(512), dim3(256), 0, stream>>>(qT, kT, Spart, Mpart);
  finalize_k<<<dim3(64), dim3(64), 0, stream>>>(Spart, Mpart, corrT);
  attn_k<<<dim3(2048), dim3(256), 0, stream>>>(vb, corrT, qT);
  gemm_bt<2><<<dim3(2048), dim3(256), 0, stream>>>(qT, Woutb, bout, d_out,
                                                   32768, 1024, 1024, 8);
}

// Round 4
// 684.612 us; speedup vs baseline: 1.1749x; 1.1749x over previous
//
#include <hip/hip_runtime.h>
#include <stdint.h>

// MultiheadCorrelation: T=8192, B=4, D=1024, H=16, hd=64. fp32 I/O, bf16 MFMA inside.
// cvt -> gemm_qk (A=Wqkv, B=query per-b: writes qT/kT [bh][d][t] natively coalesced)
//     -> gemm_v (natural [t*4+b][1024]) -> stats (MFMA partials) -> finalize
//     -> attn (v@corr MFMA) -> gemm2 (fp32 out).

typedef unsigned short u16;
typedef __attribute__((ext_vector_type(8))) short bf16x8;
typedef __attribute__((ext_vector_type(8))) u16  u16x8;
typedef __attribute__((ext_vector_type(4))) float f32x4;

#define AS1 __attribute__((address_space(1)))
#define AS3 __attribute__((address_space(3)))

__device__ __forceinline__ u16 f2b(float f) {
  union { float f; uint32_t u; } x; x.f = f;
  const uint32_t u = x.u;
  return (u16)((u + 0x7FFFu + ((u >> 16) & 1u)) >> 16);  // RNE
}
__device__ __forceinline__ void g2l16(const void* g, void* l) {
  __builtin_amdgcn_global_load_lds((const AS1 uint32_t*)g, (AS3 uint32_t*)l, 16, 0, 0);
}

// ---------------------------------------------------------------------------
// fused fp32->bf16 convert for query / Wqkv / Wout (one launch)
// ---------------------------------------------------------------------------
__global__ __launch_bounds__(256) void cvt_all(
    const float* __restrict__ q, const float* __restrict__ w1, const float* __restrict__ w2,
    u16* __restrict__ qb, u16* __restrict__ w1b, u16* __restrict__ w2b)
{
  int i = blockIdx.x * 256 + threadIdx.x;
  if (i >= 4718592) return;
  const float* s; u16* d; int ofs;
  if (i < 4194304)      { s = q;  d = qb;  ofs = i; }
  else if (i < 4587520) { s = w1; d = w1b; ofs = i - 4194304; }
  else                  { s = w2; d = w2b; ofs = i - 4587520; }
  const float4 a = *(const float4*)(s + (size_t)ofs * 8);
  const float4 b = *(const float4*)(s + (size_t)ofs * 8 + 4);
  u16x8 o;
  o[0] = f2b(a.x); o[1] = f2b(a.y); o[2] = f2b(a.z); o[3] = f2b(a.w);
  o[4] = f2b(b.x); o[5] = f2b(b.y); o[6] = f2b(b.z); o[7] = f2b(b.w);
  *(u16x8*)(d + (size_t)ofs * 8) = o;
}

// ---------------------------------------------------------------------------
// gemm_qk: C[f][t] = sum_k W[f,k] * Q[t*4+b, k] + bias[f], for f in [0,2048).
// Output written to qkT[seg][(b*16+h)*64+d][8192 t] (seg=f>>10, h=(f&1023)>>6, d=f&63).
// Stores: lane&15 -> consecutive t => 32B runs, full line coverage per wave.
// grid = 64 t-tiles * 16 f-tiles * 4 b. 128x128 tile, BK=64, XOR-swizzled LDS.
// ---------------------------------------------------------------------------
__global__ __launch_bounds__(256) void gemm_qk(
    const u16* __restrict__ W, const u16* __restrict__ Q,
    const float* __restrict__ bias, u16* __restrict__ qkT)
{
  __shared__ __align__(16) u16 As[128 * 64];   // W tile (f-major)
  __shared__ __align__(16) u16 Bs[128 * 64];   // query tile (t-major)
  const int tid = threadIdx.x;
  const int bn = blockIdx.x & 63;          // t-tile
  const int bm = (blockIdx.x >> 6) & 15;   // f-tile
  const int b  = blockIdx.x >> 10;         // batch
  const int m0 = bm * 128, n0 = bn * 128;  // f0, t0
  const int lane = tid & 63, wave = tid >> 6;
  const int wm = (wave >> 1) * 64, wn = (wave & 1) * 64;
  const int laneN = lane & 15, laneQ = lane >> 4;

  const int srow = tid >> 3;
  const int skb  = (tid & 7) ^ (srow & 7);
  const u16* gA = W + (size_t)(m0 + srow) * 1024 + skb * 8;
  const u16* gB = Q + ((size_t)(n0 + srow) * 4 + b) * 1024 + skb * 8;
  u16* lA = &As[tid * 8];
  u16* lB = &Bs[tid * 8];

  f32x4 acc[4][4] = {};

  for (int kt = 0; kt < 1024; kt += 64) {
    __syncthreads();
#pragma unroll
    for (int i = 0; i < 4; ++i) {
      g2l16(gA + kt + (size_t)(i * 32) * 1024, lA + i * 2048);
      g2l16(gB + kt + (size_t)(i * 32) * 4096, lB + i * 2048);
    }
    __syncthreads();
#pragma unroll
    for (int ks2 = 0; ks2 < 2; ++ks2) {
      bf16x8 af[4], bf[4];
#pragma unroll
      for (int i = 0; i < 4; ++i) {
        const int row = wm + i * 16 + laneN;
        const int kq  = (ks2 * 4 + laneQ) ^ (row & 7);
        af[i] = *(const bf16x8*)&As[row * 64 + kq * 8];
      }
#pragma unroll
      for (int j = 0; j < 4; ++j) {
        const int row = wn + j * 16 + laneN;
        const int kq  = (ks2 * 4 + laneQ) ^ (row & 7);
        bf[j] = *(const bf16x8*)&Bs[row * 64 + kq * 8];
      }
#pragma unroll
      for (int i = 0; i < 4; ++i)
#pragma unroll
        for (int j = 0; j < 4; ++j)
          acc[i][j] = __builtin_amdgcn_mfma_f32_16x16x32_bf16(af[i], bf[j], acc[i][j], 0, 0, 0);
    }
  }

#pragma unroll
  for (int i = 0; i < 4; ++i) {
#pragma unroll
    for (int r = 0; r < 4; ++r) {
      const int f = m0 + wm + i * 16 + laneQ * 4 + r;   // C/D: row=quad*4+r (m=f)
      const float bv = bias[f];
      const int seg = f >> 10, h = (f & 1023) >> 6, d = f & 63;
      u16* base = qkT + (size_t)seg * 33554432 +
                  ((size_t)((b * 16 + h) * 64 + d)) * 8192;
#pragma unroll
      for (int j = 0; j < 4; ++j) {
        const int t = n0 + wn + j * 16 + laneN;         // col=lane&15 (n=t)
        base[t] = f2b(acc[i][j][r] + bv);
      }
    }
  }
}

// ---------------------------------------------------------------------------
// gemm_bt: C[m,n] = sum_k A[m,k]*Bw[n,k] + bias[n]. 128x128, BK=64, swizzled.
// MODE 0: bf16 [M,N] out. MODE 2: fp32 [M,N] out.
// ---------------------------------------------------------------------------
template <int MODE>
__global__ __launch_bounds__(256) void gemm_bt(
    const u16* __restrict__ A, const u16* __restrict__ Bw,
    const float* __restrict__ bias, void* __restrict__ OutP,
    int M, int N, int K, int nTilesN)
{
  __shared__ __align__(16) u16 As[128 * 64];
  __shared__ __align__(16) u16 Bs[128 * 64];
  const int tid = threadIdx.x;
  const int bn = blockIdx.x % nTilesN;
  const int bm = blockIdx.x / nTilesN;
  const int m0 = bm * 128, n0 = bn * 128;
  const int lane = tid & 63, wave = tid >> 6;
  const int wm = (wave >> 1) * 64, wn = (wave & 1) * 64;
  const int laneN = lane & 15, laneQ = lane >> 4;

  const int srow = tid >> 3;
  const int skb  = (tid & 7) ^ (srow & 7);
  const u16* gA = A  + (size_t)(m0 + srow) * K + skb * 8;
  const u16* gB = Bw + (size_t)(n0 + srow) * K + skb * 8;
  u16* lA = &As[tid * 8];
  u16* lB = &Bs[tid * 8];

  f32x4 acc[4][4] = {};

  for (int kt = 0; kt < K; kt += 64) {
    __syncthreads();
#pragma unroll
    for (int i = 0; i < 4; ++i) {
      g2l16(gA + kt + (size_t)(i * 32) * K, lA + i * 2048);
      g2l16(gB + kt + (size_t)(i * 32) * K, lB + i * 2048);
    }
    __syncthreads();
#pragma unroll
    for (int ks2 = 0; ks2 < 2; ++ks2) {
      bf16x8 af[4], bf[4];
#pragma unroll
      for (int i = 0; i < 4; ++i) {
        const int row = wm + i * 16 + laneN;
        const int kq  = (ks2 * 4 + laneQ) ^ (row & 7);
        af[i] = *(const bf16x8*)&As[row * 64 + kq * 8];
      }
#pragma unroll
      for (int j = 0; j < 4; ++j) {
        const int row = wn + j * 16 + laneN;
        const int kq  = (ks2 * 4 + laneQ) ^ (row & 7);
        bf[j] = *(const bf16x8*)&Bs[row * 64 + kq * 8];
      }
#pragma unroll
      for (int i = 0; i < 4; ++i)
#pragma unroll
        for (int j = 0; j < 4; ++j)
          acc[i][j] = __builtin_amdgcn_mfma_f32_16x16x32_bf16(af[i], bf[j], acc[i][j], 0, 0, 0);
    }
  }

#pragma unroll
  for (int i = 0; i < 4; ++i) {
#pragma unroll
    for (int j = 0; j < 4; ++j) {
      const int col = n0 + wn + j * 16 + laneN;
      const float bv = bias[col];
#pragma unroll
      for (int r = 0; r < 4; ++r) {
        const int row = m0 + wm + i * 16 + laneQ * 4 + r;
        const float v = acc[i][j][r] + bv;
        if (MODE == 0) ((u16*)OutP)[(size_t)row * N + col] = f2b(v);
        else           ((float*)OutP)[(size_t)row * N + col] = v;
      }
    }
  }
}

// ---------------------------------------------------------------------------
// Stats (MFMA): per (b,h) S[d][e]=sum_t q_d k_e, plus Sq,Sqq,Sk,Skk.
// qT,kT: [bh][64 d][8192 t] bf16. grid = 64 bh * 8 chunks, block 256.
// ---------------------------------------------------------------------------
__global__ __launch_bounds__(256) void stats_k(
    const u16* __restrict__ qT, const u16* __restrict__ kT,
    float* __restrict__ Spart, float* __restrict__ Mpart)
{
  __shared__ __align__(16) u16 smem[2 * 4 * 64 * 64];  // 64 KB
  __shared__ float margLDS[4 * 256];
  u16* Qs = smem;
  u16* Ks = smem + 16384;
  const int tid = threadIdx.x;
  const int bh = blockIdx.x & 63;
  const int chunk = blockIdx.x >> 6;
  const int t0 = chunk * 1024;
  const int lane = tid & 63, wave = tid >> 6;
  const int laneN = lane & 15, laneQ = lane >> 4;

  const u16* qp = qT + (size_t)bh * 524288;
  const u16* kp = kT + (size_t)bh * 524288;

  f32x4 accS[4][4] = {};
  f32x4 accQQ[4] = {}, accKK[4] = {}, accQ1[4] = {}, accK1[4] = {};
  bf16x8 ones;
#pragma unroll
  for (int j = 0; j < 8; ++j) ones[j] = (short)0x3F80;

  for (int rd = 0; rd < 4; ++rd) {
    __syncthreads();
#pragma unroll
    for (int i = 0; i < 8; ++i) {
      const int c = tid + i * 256;
      const int tile = c >> 9, cw = c & 511;
      const int d = cw >> 3, slot = cw & 7;
      const int kb = slot ^ (d & 7);
      const size_t gofs = (size_t)d * 8192 + (t0 + rd * 256 + tile * 64 + kb * 8);
      g2l16(qp + gofs, &Qs[c * 8]);
      g2l16(kp + gofs, &Ks[c * 8]);
    }
    __syncthreads();
    const u16* qt = &Qs[wave * 4096];
    const u16* kt2 = &Ks[wave * 4096];
#pragma unroll
    for (int ks2 = 0; ks2 < 2; ++ks2) {
      bf16x8 qf[4], kf[4];
#pragma unroll
      for (int i = 0; i < 4; ++i) {
        const int d = i * 16 + laneN;
        const int kq = (ks2 * 4 + laneQ) ^ (d & 7);
        qf[i] = *(const bf16x8*)&qt[d * 64 + kq * 8];
        kf[i] = *(const bf16x8*)&kt2[d * 64 + kq * 8];
      }
#pragma unroll
      for (int i = 0; i < 4; ++i) {
#pragma unroll
        for (int j = 0; j < 4; ++j)
          accS[i][j] = __builtin_amdgcn_mfma_f32_16x16x32_bf16(qf[i], kf[j], accS[i][j], 0, 0, 0);
        accQQ[i] = __builtin_amdgcn_mfma_f32_16x16x32_bf16(qf[i], qf[i], accQQ[i], 0, 0, 0);
        accKK[i] = __builtin_amdgcn_mfma_f32_16x16x32_bf16(kf[i], kf[i], accKK[i], 0, 0, 0);
        accQ1[i] = __builtin_amdgcn_mfma_f32_16x16x32_bf16(qf[i], ones, accQ1[i], 0, 0, 0);
        accK1[i] = __builtin_amdgcn_mfma_f32_16x16x32_bf16(kf[i], ones, accK1[i], 0, 0, 0);
      }
    }
  }

  __syncthreads();
  float* red = (float*)smem;
#pragma unroll
  for (int i = 0; i < 4; ++i)
#pragma unroll
    for (int j = 0; j < 4; ++j)
#pragma unroll
      for (int r = 0; r < 4; ++r) {
        const int d = i * 16 + laneQ * 4 + r, e = j * 16 + laneN;
        red[wave * 4096 + d * 64 + e] = accS[i][j][r];
      }
#pragma unroll
  for (int i = 0; i < 4; ++i) {
    if (laneN == 0) {
#pragma unroll
      for (int r = 0; r < 4; ++r) {
        const int d = i * 16 + laneQ * 4 + r;
        margLDS[wave * 256 + 0 * 64 + d] = accQ1[i][r];
        margLDS[wave * 256 + 2 * 64 + d] = accK1[i][r];
      }
    }
    if ((laneN >> 2) == laneQ) {
      const int r = laneN & 3;
      const int d = i * 16 + laneN;
      margLDS[wave * 256 + 1 * 64 + d] = accQQ[i][r];
      margLDS[wave * 256 + 3 * 64 + d] = accKK[i][r];
    }
  }
  __syncthreads();
  float* Sp = Spart + ((size_t)chunk * 64 + bh) * 4096;
  for (int c = tid; c < 4096; c += 256)
    Sp[c] = red[c] + red[4096 + c] + red[8192 + c] + red[12288 + c];
  float* Mp = Mpart + ((size_t)chunk * 64 + bh) * 256;
  Mp[tid] = margLDS[tid] + margLDS[256 + tid] + margLDS[512 + tid] + margLDS[768 + tid];
}

// ---------------------------------------------------------------------------
// Finalize: sum partials; corr=clip(cov/sqrt(sx sy),0,1); softmax over d;
// store corrT[e][d] bf16. grid 64 (bh), block 64 (e).
// ---------------------------------------------------------------------------
__global__ __launch_bounds__(64) void finalize_k(
    const float* __restrict__ Spart, const float* __restrict__ Mpart,
    u16* __restrict__ corrT)
{
  __shared__ float Ss[4096];
  __shared__ float sqs[64], sxs[64];
  const int bh = blockIdx.x;
  const int e = threadIdx.x;
  for (int idx = e; idx < 4096; idx += 64) {
    float s = 0.f;
#pragma unroll
    for (int c = 0; c < 8; ++c) s += Spart[((size_t)c * 64 + bh) * 4096 + idx];
    Ss[idx] = s;
  }
  float m[4];
#pragma unroll
  for (int p = 0; p < 4; ++p) {
    float s = 0.f;
#pragma unroll
    for (int c = 0; c < 8; ++c) s += Mpart[((size_t)c * 64 + bh) * 256 + p * 64 + e];
    m[p] = s;
  }
  const float invT = 1.0f / 8192.0f;
  const float sy = m[3] - m[2] * m[2] * invT;
  const float ske = m[2];
  sqs[e] = m[0];
  sxs[e] = m[1] - m[0] * m[0] * invT;
  __syncthreads();
  float mx = 0.0f;
  for (int d = 0; d < 64; ++d) {
    const float c = Ss[d * 64 + e] - sqs[d] * ske * invT;
    float r = c / sqrtf(sxs[d] * sy);
    r = fminf(fmaxf(r, 0.0f), 1.0f);
    Ss[d * 64 + e] = r;
    mx = fmaxf(mx, r);
  }
  float sum = 0.f;
  for (int d = 0; d < 64; ++d) {
    const float ev = expf(Ss[d * 64 + e] - mx);
    Ss[d * 64 + e] = ev;
    sum += ev;
  }
  const float inv = 1.0f / sum;
  for (int d = 0; d < 64; ++d)
    corrT[(size_t)bh * 4096 + e * 64 + d] = f2b(Ss[d * 64 + e] * inv);
}

// ---------------------------------------------------------------------------
// Attn: attn[t,e] = sum_d v[t,d]*corr[d,e] per (b,h). A=v natural, B^T=corrT.
// grid = 64 bh * 32 t-tiles(256), block 256.
// ---------------------------------------------------------------------------
__global__ __launch_bounds__(256) void attn_k(
    const u16* __restrict__ vb, const u16* __restrict__ corrT,
    u16* __restrict__ attnb)
{
  __shared__ __align__(16) u16 Vs[256 * 64];
  __shared__ __align__(16) u16 Cs[64 * 64];
  const int tid = threadIdx.x;
  const int bh = blockIdx.x & 63;
  const int tt0 = (blockIdx.x >> 6) * 256;
  const int b = bh >> 4, h = bh & 15;
  const int lane = tid & 63, wave = tid >> 6;
  const int laneN = lane & 15, laneQ = lane >> 4;

  {
#pragma unroll
    for (int i = 0; i < 8; ++i) {
      const int c = tid + i * 256;
      const int row = c >> 3, slot = c & 7;
      const int kb = slot ^ (row & 7);
      const u16* g = vb + (size_t)((tt0 + row) * 4 + b) * 1024 + h * 64 + kb * 8;
      g2l16(g, &Vs[c * 8]);
    }
#pragma unroll
    for (int i = 0; i < 2; ++i) {
      const int c = tid + i * 256;
      const int row = c >> 3, slot = c & 7;
      const int kb = slot ^ (row & 7);
      g2l16(corrT + (size_t)bh * 4096 + row * 64 + kb * 8, &Cs[c * 8]);
    }
  }
  __syncthreads();

  const int wt = wave * 64;
  f32x4 acc[4][4] = {};
#pragma unroll
  for (int ks2 = 0; ks2 < 2; ++ks2) {
    bf16x8 af[4], bf[4];
#pragma unroll
    for (int i = 0; i < 4; ++i) {
      const int row = wt + i * 16 + laneN;
      const int kq = (ks2 * 4 + laneQ) ^ (row & 7);
      af[i] = *(const bf16x8*)&Vs[row * 64 + kq * 8];
    }
#pragma unroll
    for (int j = 0; j < 4; ++j) {
      const int row = j * 16 + laneN;
      const int kq = (ks2 * 4 + laneQ) ^ (row & 7);
      bf[j] = *(const bf16x8*)&Cs[row * 64 + kq * 8];
    }
#pragma unroll
    for (int i = 0; i < 4; ++i)
#pragma unroll
      for (int j = 0; j < 4; ++j)
        acc[i][j] = __builtin_amdgcn_mfma_f32_16x16x32_bf16(af[i], bf[j], acc[i][j], 0, 0, 0);
  }
#pragma unroll
  for (int i = 0; i < 4; ++i)
#pragma unroll
    for (int j = 0; j < 4; ++j)
#pragma unroll
      for (int r = 0; r < 4; ++r) {
        const int t = tt0 + wt + i * 16 + laneQ * 4 + r;
        const int e = j * 16 + laneN;
        attnb[(size_t)(t * 4 + b) * 1024 + h * 64 + e] = f2b(acc[i][j][r]);
      }
}

// ---------------------------------------------------------------------------
// ws layout (bytes):
//   0          qT   [64bh][64][8192] bf16 (64 MiB) -> reused as attn out [32768][1024]
//   67108864   kT   (64 MiB)
//   134217728  vb   [32768][1024] bf16 (64 MiB)
//   201326592  queryb (64 MiB)  -- dead after gemms, aliased by:
//     201326592  Spart 8*64*4096 f32 (8 MiB)
//     209715200  Mpart 8*64*256 f32 (512 KiB)
//     210239488  corrT 64*4096 bf16 (512 KiB)
//   268435456  Wqkvb (6 MiB)
//   274726912  Woutb (2 MiB)
// ---------------------------------------------------------------------------
extern "C" void kernel_launch(void* const* d_in, const int* in_sizes, int n_in,
                              void* d_out, int out_size, void* d_ws, size_t ws_size,
                              hipStream_t stream)
{
  const float* query = (const float*)d_in[0];
  const float* Wqkv  = (const float*)d_in[1];
  const float* bqkv  = (const float*)d_in[2];
  const float* Wout  = (const float*)d_in[3];
  const float* bout  = (const float*)d_in[4];
  char* ws = (char*)d_ws;

  u16*   qkT    = (u16*)(ws);                 // q seg then k seg
  u16*   kT     = (u16*)(ws + 67108864);
  u16*   vb     = (u16*)(ws + 134217728);
  u16*   queryb = (u16*)(ws + 201326592);
  float* Spart  = (float*)(ws + 201326592);
  float* Mpart  = (float*)(ws + 209715200);
  u16*   corrT  = (u16*)(ws + 210239488);
  u16*   Wqkvb  = (u16*)(ws + 268435456);
  u16*   Woutb  = (u16*)(ws + 274726912);

  cvt_all<<<dim3(18432), dim3(256), 0, stream>>>(query, Wqkv, Wout, queryb, Wqkvb, Woutb);

  // q,k features (2048) in swapped orientation -> [bh][d][t] natively
  gemm_qk<<<dim3(4096), dim3(256), 0, stream>>>(Wqkvb, queryb, bqkv, qkT);
  // v features (1024) in original orientation -> natural [t*4+b][1024]
  gemm_bt<0><<<dim3(2048), dim3(256), 0, stream>>>(queryb, Wqkvb + (size_t)2048 * 1024,
                                                   bqkv + 2048, vb, 32768, 1024, 1024, 8);
  stats_k<<<dim3(512), dim3(256), 0, stream>>>(qkT, kT, Spart, Mpart);
  finalize_k<<<dim3(64), dim3(64), 0, stream>>>(Spart, Mpart, corrT);
  attn_k<<<dim3(2048), dim3(256), 0, stream>>>(vb, corrT, qkT);
  gemm_bt<2><<<dim3(2048), dim3(256), 0, stream>>>(qkT, Woutb, bout, d_out,
                                                   32768, 1024, 1024, 8);
}